// Round 6
// baseline (1544.783 us; speedup 1.0000x reference)
//
#include <hip/hip_runtime.h>
#include <math.h>

#define Bq 8
#define Lq 65536
#define Hq 32
#define Nq 8
#define DEPq 4
#define LCq 128
#define NCq (Lq/LCq)   // 512

// ---------------- conditioning MLP + FiLM ----------------
// grid = DEPq blocks (one per depth d), 512 threads: b = tid>>6, k = tid&63
__global__ void k_cond_film(const float* __restrict__ prm,
                            const float* __restrict__ W1, const float* __restrict__ b1,
                            const float* __restrict__ W2, const float* __restrict__ b2,
                            const float* __restrict__ W3, const float* __restrict__ b3,
                            const float* __restrict__ filmW, const float* __restrict__ filmB,
                            float* __restrict__ film /* [DEP][B][2H] */)
{
    __shared__ float cond[Bq][32];
    int tid = threadIdx.x, d = blockIdx.x;
    if (tid < Bq) {
        float p0 = prm[tid*2+0], p1 = prm[tid*2+1];
        float c1[16];
        #pragma unroll
        for (int i=0;i<16;i++){ float v = W1[i*2+0]*p0 + W1[i*2+1]*p1 + b1[i]; c1[i]=v>0.f?v:0.f; }
        float c2[32];
        #pragma unroll
        for (int i=0;i<32;i++){ float a=b2[i];
            #pragma unroll
            for(int j=0;j<16;j++) a = fmaf(W2[i*16+j], c1[j], a);
            c2[i]=a>0.f?a:0.f; }
        #pragma unroll
        for (int i=0;i<32;i++){ float a=b3[i];
            #pragma unroll
            for(int j=0;j<32;j++) a = fmaf(W3[i*32+j], c2[j], a);
            cond[tid][i]=a>0.f?a:0.f; }
    }
    __syncthreads();
    int b = tid>>6, k = tid&63;                      // k in [0,64)
    float a = filmB[d*2*Hq + k];
    #pragma unroll
    for (int j=0;j<32;j++) a = fmaf(cond[b][j], filmW[(d*2*Hq + k)*32 + j], a);
    film[(d*Bq + b)*2*Hq + k] = a;
}

// ---------------- S4D derived params (f64) ----------------
// 1 block, 1024 threads = DEP*H*N
__global__ void k_s4params(const float* __restrict__ log_dt, const float* __restrict__ logAre,
                           const float* __restrict__ Aim_, const float* __restrict__ Cre_,
                           const float* __restrict__ Cim_,
                           double* __restrict__ pw, double* __restrict__ pc2,
                           double* __restrict__ pwL)
{
    int idx = threadIdx.x; // DEP*H*N = 1024
    int d = idx/(Hq*Nq); int h = (idx/Nq)%Hq;
    double dt = exp((double)log_dt[d*Hq+h]);
    double Are = -exp((double)logAre[idx]);
    double Aim = (double)Aim_[idx];
    double dar = dt*Are, dai = dt*Aim;
    double er = exp(dar);
    double wr = er*cos(dai), wi = er*sin(dai);
    double em1r = wr - 1.0, em1i = wi;                 // exp(dtA)-1
    double den = Are*Are + Aim*Aim;
    double qr = (em1r*Are + em1i*Aim)/den;             // (exp(dtA)-1)/A
    double qi = (em1i*Are - em1r*Aim)/den;
    double Cr = (double)Cre_[idx], Ci = (double)Cim_[idx];
    double eL = exp(dar*(double)LCq);
    pw[idx*2+0]=wr;  pw[idx*2+1]=wi;
    pc2[idx*2+0]=2.0*(Cr*qr - Ci*qi); pc2[idx*2+1]=2.0*(Cr*qi + Ci*qr);
    pwL[idx*2+0]=eL*cos(dai*(double)LCq); pwL[idx*2+1]=eL*sin(dai*(double)LCq);
}

// ---------------- expand: h[b,h,l] = x[b,l]*eW[h] + eb[h] ----------------
__global__ void k_expand(const float* __restrict__ x, const float* __restrict__ eW,
                         const float* __restrict__ eb, float* __restrict__ hbuf)
{
    int idx = blockIdx.x*blockDim.x + threadIdx.x;   // B*H*L
    int l = idx & (Lq-1); int bh = idx >> 16; int h = bh & (Hq-1); int b = bh >> 5;
    hbuf[idx] = fmaf(x[b*Lq + l], eW[h], eb[h]);
}

// ---------------- 32x32 channel mix + ReLU ----------------
__global__ void k_mix(const float* __restrict__ hbuf, const float* __restrict__ linW,
                      const float* __restrict__ linB, float* __restrict__ ubuf)
{
    int idx = blockIdx.x*blockDim.x + threadIdx.x;   // B*L
    int b = idx >> 16; int l = idx & (Lq-1);
    float hv[Hq];
    #pragma unroll
    for (int g=0; g<Hq; g++) hv[g] = hbuf[((size_t)(b*Hq+g))*Lq + l];
    #pragma unroll
    for (int g=0; g<Hq; g++) {
        float a = linB[g];
        #pragma unroll
        for (int h2=0; h2<Hq; h2++) a = fmaf(linW[g*Hq+h2], hv[h2], a);
        ubuf[((size_t)(b*Hq+g))*Lq + l] = a>0.f?a:0.f;
    }
}

// ---------------- pass1: chunk-local end states (f64 state) ----------------
__global__ void k_pass1(const float* __restrict__ ubuf, const double* __restrict__ pw,
                        double* __restrict__ sloc)
{
    int t = blockIdx.x*blockDim.x + threadIdx.x; // B*H*NC = 131072
    int c = t & (NCq-1); int bh = t >> 9; int h = bh & (Hq-1);
    const float* up = ubuf + (size_t)bh*Lq + (size_t)c*LCq;
    double wr[Nq], wi[Nq], sr[Nq], si[Nq];
    #pragma unroll
    for (int n=0;n<Nq;n++){ wr[n]=pw[(h*Nq+n)*2]; wi[n]=pw[(h*Nq+n)*2+1]; sr[n]=0.0; si[n]=0.0; }
    for (int j=0;j<LCq;j+=4){
        float4 uv = *reinterpret_cast<const float4*>(up + j);
        float us[4] = {uv.x,uv.y,uv.z,uv.w};
        #pragma unroll
        for (int k=0;k<4;k++){
            double u = (double)us[k];
            #pragma unroll
            for (int n=0;n<Nq;n++){
                double nr = fma(wr[n], sr[n], fma(-wi[n], si[n], u));
                double ni = fma(wr[n], si[n], wi[n]*sr[n]);
                sr[n]=nr; si[n]=ni;
            }
        }
    }
    double* sp = sloc + (size_t)t*2*Nq;
    #pragma unroll
    for (int n=0;n<Nq;n++){ sp[n]=sr[n]; sp[Nq+n]=si[n]; }
}

// ---------------- pass2: prefix over chunks (f64, exact w^LC step) ----------------
__global__ void k_pass2(const double* __restrict__ sloc, const double* __restrict__ pwL,
                        double* __restrict__ sini)
{
    int t = blockIdx.x*blockDim.x + threadIdx.x; // B*H*N = 2048
    int n = t & (Nq-1); int bh = t >> 3; int h = bh & (Hq-1);
    double wLr = pwL[(h*Nq+n)*2], wLi = pwL[(h*Nq+n)*2+1];
    double cr=0.0, ci=0.0;
    for (int c=0;c<NCq;c++){
        size_t off = ((size_t)bh*NCq + c)*2*Nq;
        sini[off+n] = cr; sini[off+Nq+n] = ci;
        double lr = sloc[off+n], li = sloc[off+Nq+n];
        double nr = fma(wLr,cr, fma(-wLi,ci, lr));
        double ni = fma(wLr,ci, fma( wLi,cr, li));
        cr=nr; ci=ni;
    }
}

// ---------------- pass3: seeded f64 scan + output + FiLM + ReLU + residual ----------------
__global__ void k_pass3(const float* __restrict__ ubuf, const double* __restrict__ pw,
                        const double* __restrict__ pc2, const double* __restrict__ sini,
                        const float* __restrict__ Dskip, const float* __restrict__ film,
                        const float* __restrict__ resw, float* __restrict__ hbuf)
{
    int t = blockIdx.x*blockDim.x + threadIdx.x; // B*H*NC
    int c = t & (NCq-1); int bh = t >> 9; int h = bh & (Hq-1); int b = bh >> 5;
    const float* up = ubuf + (size_t)bh*Lq + (size_t)c*LCq;
    float* hp = hbuf + (size_t)bh*Lq + (size_t)c*LCq;
    double wr[Nq],wi[Nq],cr2[Nq],ci2[Nq],sr[Nq],si[Nq];
    #pragma unroll
    for (int n=0;n<Nq;n++){
        wr[n]=pw[(h*Nq+n)*2]; wi[n]=pw[(h*Nq+n)*2+1];
        cr2[n]=pc2[(h*Nq+n)*2]; ci2[n]=pc2[(h*Nq+n)*2+1];
    }
    size_t soff = ((size_t)bh*NCq + c)*2*Nq;
    #pragma unroll
    for (int n=0;n<Nq;n++){ sr[n]=sini[soff+n]; si[n]=sini[soff+Nq+n]; }
    double D = (double)Dskip[h];
    float g = film[b*2*Hq + h], bb = film[b*2*Hq + Hq + h];
    float rw = resw[h];
    for (int j=0;j<LCq;j+=4){
        float4 uv = *reinterpret_cast<const float4*>(up + j);
        float4 hv = *reinterpret_cast<const float4*>(hp + j);
        float us[4]={uv.x,uv.y,uv.z,uv.w};
        float hs[4]={hv.x,hv.y,hv.z,hv.w};
        float ys[4];
        #pragma unroll
        for (int k=0;k<4;k++){
            double u=(double)us[k];
            double y = D*u;
            #pragma unroll
            for (int n=0;n<Nq;n++){
                double nr = fma(wr[n], sr[n], fma(-wi[n], si[n], u));
                double ni = fma(wr[n], si[n], wi[n]*sr[n]);
                sr[n]=nr; si[n]=ni;
                y = fma(cr2[n], nr, y);
                y = fma(-ci2[n], ni, y);
            }
            float yf = (float)y;
            yf = fmaf(yf, g, bb);
            yf = yf>0.f?yf:0.f;
            ys[k] = fmaf(rw, hs[k], yf);
        }
        *reinterpret_cast<float4*>(hp + j) = make_float4(ys[0],ys[1],ys[2],ys[3]);
    }
}

// ---------------- contract + tanh + side-chain ----------------
__global__ void k_contract(const float* __restrict__ hbuf, const float* __restrict__ x,
                           const float* __restrict__ cW, const float* __restrict__ cb,
                           float* __restrict__ out)
{
    int idx = blockIdx.x*blockDim.x + threadIdx.x;  // B*L
    int b = idx >> 16; int l = idx & (Lq-1);
    float a = cb[0];
    #pragma unroll
    for (int h=0;h<Hq;h++) a = fmaf(hbuf[((size_t)(b*Hq+h))*Lq + l], cW[h], a);
    out[idx] = x[idx]*tanhf(a);
}

// ---------------- diagnostic flag ----------------
__global__ void k_flag(float* __restrict__ out, int code) { out[0] = (float)code; }

extern "C" void kernel_launch(void* const* d_in, const int* in_sizes, int n_in,
                              void* d_out, int out_size, void* d_ws, size_t ws_size,
                              hipStream_t stream)
{
    const float* x    = (const float*)d_in[0];
    const float* prm  = (const float*)d_in[1];
    const float* W1   = (const float*)d_in[2];  const float* b1 = (const float*)d_in[3];
    const float* W2   = (const float*)d_in[4];  const float* b2 = (const float*)d_in[5];
    const float* W3   = (const float*)d_in[6];  const float* b3 = (const float*)d_in[7];
    const float* eW   = (const float*)d_in[8];  const float* eb = (const float*)d_in[9];
    const float* linW = (const float*)d_in[10]; const float* linB = (const float*)d_in[11];
    const float* log_dt = (const float*)d_in[12]; const float* logAre = (const float*)d_in[13];
    const float* Aim  = (const float*)d_in[14]; const float* Cre = (const float*)d_in[15];
    const float* Cim  = (const float*)d_in[16]; const float* Dskip = (const float*)d_in[17];
    const float* filmW= (const float*)d_in[18]; const float* filmB = (const float*)d_in[19];
    const float* resw = (const float*)d_in[20]; const float* cW = (const float*)d_in[21];
    const float* cb   = (const float*)d_in[22];

    // workspace layout (f64 first for alignment)
    double* sloc = (double*)d_ws;                                  // B*H*NC*2N = 2097152 d
    double* sini = sloc + (size_t)Bq*Hq*NCq*2*Nq;                  // 2097152 d
    double* pw   = sini + (size_t)Bq*Hq*NCq*2*Nq;                  // 2048 d
    double* pc2  = pw  + DEPq*Hq*Nq*2;                             // 2048 d
    double* pwL  = pc2 + DEPq*Hq*Nq*2;                             // 2048 d
    float* hbuf  = (float*)(pwL + DEPq*Hq*Nq*2);                   // B*H*L = 16777216 f
    float* ubuf  = hbuf + (size_t)Bq*Hq*Lq;                        // 16777216 f
    float* film  = ubuf + (size_t)Bq*Hq*Lq;                        // DEP*B*2H = 2048 f
    float* out   = (float*)d_out;
    size_t ws_needed = (char*)(film + DEPq*Bq*2*Hq) - (char*)d_ws;

    hipLaunchKernelGGL(k_cond_film, dim3(DEPq), dim3(512), 0, stream,
                       prm,W1,b1,W2,b2,W3,b3,filmW,filmB,film);
    hipLaunchKernelGGL(k_s4params, dim3(1), dim3(DEPq*Hq*Nq), 0, stream,
                       log_dt,logAre,Aim,Cre,Cim,pw,pc2,pwL);
    hipLaunchKernelGGL(k_expand, dim3((Bq*Hq*Lq)/256), dim3(256), 0, stream, x,eW,eb,hbuf);
    for (int d=0; d<DEPq; d++){
        hipLaunchKernelGGL(k_mix,   dim3(Bq*Lq/256),        dim3(256), 0, stream,
                           hbuf, linW + d*Hq*Hq, linB + d*Hq, ubuf);
        hipLaunchKernelGGL(k_pass1, dim3(Bq*Hq*NCq/256),    dim3(256), 0, stream,
                           ubuf, pw + d*Hq*Nq*2, sloc);
        hipLaunchKernelGGL(k_pass2, dim3(Bq*Hq*Nq/256),     dim3(256), 0, stream,
                           sloc, pwL + d*Hq*Nq*2, sini);
        hipLaunchKernelGGL(k_pass3, dim3(Bq*Hq*NCq/256),    dim3(256), 0, stream,
                           ubuf, pw + d*Hq*Nq*2, pc2 + d*Hq*Nq*2, sini,
                           Dskip + d*Hq, film + d*Bq*2*Hq, resw + d*Hq, hbuf);
    }
    hipLaunchKernelGGL(k_contract, dim3(Bq*Lq/256), dim3(256), 0, stream, hbuf, x, cW, cb, out);

    // diagnostics: input-size guard (code 100+i / 99) and ws-size guard (code 200)
    static const int expected[23] = {
        Bq*Lq, Bq*2, 32, 16, 512, 32, 1024, 32, Hq, Hq,
        DEPq*Hq*Hq, DEPq*Hq, DEPq*Hq, DEPq*Hq*Nq, DEPq*Hq*Nq, DEPq*Hq*Nq, DEPq*Hq*Nq,
        DEPq*Hq, DEPq*2*Hq*32, DEPq*2*Hq, DEPq*Hq, Hq, 1
    };
    int code = 0;
    if (n_in != 23) code = 99;
    else { for (int i = 0; i < 23; i++) if (in_sizes[i] != expected[i]) { code = 100 + i; break; } }
    if (!code && ws_size < ws_needed) code = 200;
    if (code) hipLaunchKernelGGL(k_flag, dim3(1), dim3(1), 0, stream, out, code);
}

// Round 7
// 596.476 us; speedup vs baseline: 2.5898x; 2.5898x over previous
//
#include <hip/hip_runtime.h>
#include <math.h>

#define Bq 8
#define Lq 65536
#define Hq 32
#define Nq 8
#define DEPq 4
#define LCq 128
#define NCq (Lq/LCq)   // 512

// ---------------- conditioning MLP + FiLM ----------------
__global__ void k_cond_film(const float* __restrict__ prm,
                            const float* __restrict__ W1, const float* __restrict__ b1,
                            const float* __restrict__ W2, const float* __restrict__ b2,
                            const float* __restrict__ W3, const float* __restrict__ b3,
                            const float* __restrict__ filmW, const float* __restrict__ filmB,
                            float* __restrict__ film /* [DEP][B][2H] */)
{
    __shared__ float cond[Bq][32];
    int tid = threadIdx.x, d = blockIdx.x;
    if (tid < Bq) {
        float p0 = prm[tid*2+0], p1 = prm[tid*2+1];
        float c1[16];
        #pragma unroll
        for (int i=0;i<16;i++){ float v = W1[i*2+0]*p0 + W1[i*2+1]*p1 + b1[i]; c1[i]=v>0.f?v:0.f; }
        float c2[32];
        #pragma unroll
        for (int i=0;i<32;i++){ float a=b2[i];
            #pragma unroll
            for(int j=0;j<16;j++) a = fmaf(W2[i*16+j], c1[j], a);
            c2[i]=a>0.f?a:0.f; }
        #pragma unroll
        for (int i=0;i<32;i++){ float a=b3[i];
            #pragma unroll
            for(int j=0;j<32;j++) a = fmaf(W3[i*32+j], c2[j], a);
            cond[tid][i]=a>0.f?a:0.f; }
    }
    __syncthreads();
    int b = tid>>6, k = tid&63;
    float a = filmB[d*2*Hq + k];
    #pragma unroll
    for (int j=0;j<32;j++) a = fmaf(cond[b][j], filmW[(d*2*Hq + k)*32 + j], a);
    film[(d*Bq + b)*2*Hq + k] = a;
}

// ---------------- S4D derived params (f64): w, 2C, w^128, w^2048 ----------------
__global__ void k_s4params(const float* __restrict__ log_dt, const float* __restrict__ logAre,
                           const float* __restrict__ Aim_, const float* __restrict__ Cre_,
                           const float* __restrict__ Cim_,
                           double* __restrict__ pw, double* __restrict__ pc2,
                           double* __restrict__ pwL, double* __restrict__ pwG)
{
    int idx = threadIdx.x; // DEP*H*N = 1024
    int d = idx/(Hq*Nq); int h = (idx/Nq)%Hq;
    double dt = exp((double)log_dt[d*Hq+h]);
    double Are = -exp((double)logAre[idx]);
    double Aim = (double)Aim_[idx];
    double dar = dt*Are, dai = dt*Aim;
    double er = exp(dar);
    double wr = er*cos(dai), wi = er*sin(dai);
    double em1r = wr - 1.0, em1i = wi;
    double den = Are*Are + Aim*Aim;
    double qr = (em1r*Are + em1i*Aim)/den;
    double qi = (em1i*Are - em1r*Aim)/den;
    double Cr = (double)Cre_[idx], Ci = (double)Cim_[idx];
    double eL = exp(dar*(double)LCq);
    double eG = exp(dar*(double)(LCq*16));
    pw [idx*2+0]=wr;  pw [idx*2+1]=wi;
    pc2[idx*2+0]=2.0*(Cr*qr - Ci*qi); pc2[idx*2+1]=2.0*(Cr*qi + Ci*qr);
    pwL[idx*2+0]=eL*cos(dai*(double)LCq);      pwL[idx*2+1]=eL*sin(dai*(double)LCq);
    pwG[idx*2+0]=eG*cos(dai*(double)(LCq*16)); pwG[idx*2+1]=eG*sin(dai*(double)(LCq*16));
}

// ---------------- expand: hbuf[b][l][h] = x[b,l]*eW[h] + eb[h] ----------------
__global__ void k_expand(const float* __restrict__ x, const float* __restrict__ eW,
                         const float* __restrict__ eb, float* __restrict__ hbuf)
{
    int idx = blockIdx.x*blockDim.x + threadIdx.x;   // B*L
    float xv = x[idx];
    float* rec = hbuf + (size_t)idx*Hq;
    float4 o[8];
    #pragma unroll
    for (int h=0; h<Hq; h++) ((float*)o)[h] = fmaf(xv, eW[h], eb[h]);
    #pragma unroll
    for (int k=0; k<8; k++) reinterpret_cast<float4*>(rec)[k] = o[k];
}

// ---------------- 32x32 channel mix + ReLU  (record per thread) ----------------
__global__ void k_mix(const float* __restrict__ hbuf, const float* __restrict__ linW,
                      const float* __restrict__ linB, float* __restrict__ ubuf)
{
    int idx = blockIdx.x*blockDim.x + threadIdx.x;   // B*L
    const float* rec = hbuf + (size_t)idx*Hq;
    float hv[Hq];
    #pragma unroll
    for (int k=0;k<8;k++) reinterpret_cast<float4*>(hv)[k] = reinterpret_cast<const float4*>(rec)[k];
    float ov[Hq];
    #pragma unroll
    for (int g=0; g<Hq; g++) {
        float a = linB[g];
        #pragma unroll
        for (int h2=0; h2<Hq; h2++) a = fmaf(linW[g*Hq+h2], hv[h2], a);
        ov[g] = a>0.f?a:0.f;
    }
    float* orc = ubuf + (size_t)idx*Hq;
    #pragma unroll
    for (int k=0;k<8;k++) reinterpret_cast<float4*>(orc)[k] = reinterpret_cast<float4*>(ov)[k];
}

// ---------------- pass1: chunk-local end states; lane = h ----------------
__global__ __launch_bounds__(256) void k_pass1(const float* __restrict__ ubuf,
                        const double* __restrict__ pw, double* __restrict__ sloc)
{
    int t = blockIdx.x*blockDim.x + threadIdx.x;  // B*NC*H
    int h = t & (Hq-1); int idx2 = t >> 5; int c = idx2 & (NCq-1); int b = idx2 >> 9;
    const float* up = ubuf + ((size_t)b*Lq + (size_t)c*LCq)*Hq + h;
    double wr[Nq], wi[Nq], sr[Nq], si[Nq];
    #pragma unroll
    for (int n=0;n<Nq;n++){ wr[n]=pw[(h*Nq+n)*2]; wi[n]=pw[(h*Nq+n)*2+1]; sr[n]=0.0; si[n]=0.0; }
    for (int j=0;j<LCq;j++){
        double u = (double)up[(size_t)j*Hq];
        #pragma unroll
        for (int n=0;n<Nq;n++){
            double nr = fma(wr[n], sr[n], fma(-wi[n], si[n], u));
            double ni = fma(wr[n], si[n], wi[n]*sr[n]);
            sr[n]=nr; si[n]=ni;
        }
    }
    double* sp = sloc + ((size_t)(b*Hq+h)*NCq + c)*16;
    #pragma unroll
    for (int n=0;n<Nq;n++){ sp[n]=sr[n]; sp[Nq+n]=si[n]; }
}

// ---------------- pass2: two-level prefix over chunks, block per (b,h) ----------------
__global__ __launch_bounds__(256) void k_pass2(const double* __restrict__ sloc,
    const double* __restrict__ pwL, const double* __restrict__ pwG,
    double* __restrict__ sini)
{
    __shared__ double aux[32*Nq*2];   // per (group,n): E then P
    int bid = blockIdx.x; int b = bid >> 5, h = bid & (Hq-1);
    const double* src = sloc + (size_t)(b*Hq+h)*NCq*16;
    double*       dst = sini + (size_t)(b*Hq+h)*NCq*16;
    int tid = threadIdx.x;
    int n = tid & 7, g2 = tid >> 3;   // g2 in [0,32)
    double wLr = pwL[(h*Nq+n)*2], wLi = pwL[(h*Nq+n)*2+1];
    // phase A: group-local end states
    double sr=0.0, si=0.0;
    for (int k=0;k<16;k++){
        int c = g2*16+k;
        double lr = src[c*16+n], li = src[c*16+8+n];
        double nr = fma(wLr,sr, fma(-wLi,si, lr));
        double ni = fma(wLr,si, fma( wLi,sr, li));
        sr=nr; si=ni;
    }
    aux[(g2*8+n)*2+0]=sr; aux[(g2*8+n)*2+1]=si;
    __syncthreads();
    // phase B: scan 32 group states (8 threads)
    if (tid < 8) {
        double wGr = pwG[(h*Nq+tid)*2], wGi = pwG[(h*Nq+tid)*2+1];
        double pr=0.0, pi=0.0;
        for (int g=0; g<32; g++){
            double e_r = aux[(g*8+tid)*2+0], e_i = aux[(g*8+tid)*2+1];
            aux[(g*8+tid)*2+0] = pr; aux[(g*8+tid)*2+1] = pi;
            double nr = fma(wGr,pr, fma(-wGi,pi, e_r));
            double ni = fma(wGr,pi, fma( wGi,pr, e_i));
            pr=nr; pi=ni;
        }
    }
    __syncthreads();
    // phase C: reseed and emit per-chunk initial states
    sr = aux[(g2*8+n)*2+0]; si = aux[(g2*8+n)*2+1];
    for (int k=0;k<16;k++){
        int c = g2*16+k;
        double lr = src[c*16+n], li = src[c*16+8+n];
        dst[c*16+n] = sr; dst[c*16+8+n] = si;
        double nr = fma(wLr,sr, fma(-wLi,si, lr));
        double ni = fma(wLr,si, fma( wLi,sr, li));
        sr=nr; si=ni;
    }
}

// ---------------- pass3: seeded scan + out-proj + FiLM + ReLU + residual; lane = h ----------------
__global__ __launch_bounds__(256) void k_pass3(const float* __restrict__ ubuf,
                        const double* __restrict__ pw, const double* __restrict__ pc2,
                        const double* __restrict__ sini,
                        const float* __restrict__ Dskip, const float* __restrict__ film,
                        const float* __restrict__ resw, float* __restrict__ hbuf)
{
    int t = blockIdx.x*blockDim.x + threadIdx.x;  // B*NC*H
    int h = t & (Hq-1); int idx2 = t >> 5; int c = idx2 & (NCq-1); int b = idx2 >> 9;
    size_t base = ((size_t)b*Lq + (size_t)c*LCq)*Hq + h;
    const float* up = ubuf + base;
    float* hp = hbuf + base;
    double wr[Nq],wi[Nq],cr2[Nq],ci2[Nq],sr[Nq],si[Nq];
    #pragma unroll
    for (int n=0;n<Nq;n++){
        wr[n]=pw[(h*Nq+n)*2];  wi[n]=pw[(h*Nq+n)*2+1];
        cr2[n]=pc2[(h*Nq+n)*2]; ci2[n]=pc2[(h*Nq+n)*2+1];
    }
    const double* sp = sini + ((size_t)(b*Hq+h)*NCq + c)*16;
    #pragma unroll
    for (int n=0;n<Nq;n++){ sr[n]=sp[n]; si[n]=sp[Nq+n]; }
    double D = (double)Dskip[h];
    float g = film[b*2*Hq + h], bb = film[b*2*Hq + Hq + h];
    float rw = resw[h];
    for (int j=0;j<LCq;j++){
        double u = (double)up[(size_t)j*Hq];
        float hv = hp[(size_t)j*Hq];
        double y = D*u;
        #pragma unroll
        for (int n=0;n<Nq;n++){
            double nr = fma(wr[n], sr[n], fma(-wi[n], si[n], u));
            double ni = fma(wr[n], si[n], wi[n]*sr[n]);
            sr[n]=nr; si[n]=ni;
            y = fma(cr2[n], nr, y);
            y = fma(-ci2[n], ni, y);
        }
        float yf = (float)y;
        yf = fmaf(yf, g, bb);
        yf = yf>0.f?yf:0.f;
        hp[(size_t)j*Hq] = fmaf(rw, hv, yf);
    }
}

// ---------------- contract + tanh + side-chain ----------------
__global__ void k_contract(const float* __restrict__ hbuf, const float* __restrict__ x,
                           const float* __restrict__ cW, const float* __restrict__ cb,
                           float* __restrict__ out)
{
    int idx = blockIdx.x*blockDim.x + threadIdx.x;  // B*L
    const float* rec = hbuf + (size_t)idx*Hq;
    float hv[Hq];
    #pragma unroll
    for (int k=0;k<8;k++) reinterpret_cast<float4*>(hv)[k] = reinterpret_cast<const float4*>(rec)[k];
    float a = cb[0];
    #pragma unroll
    for (int h=0;h<Hq;h++) a = fmaf(hv[h], cW[h], a);
    out[idx] = x[idx]*tanhf(a);
}

// ---------------- diagnostic flag ----------------
__global__ void k_flag(float* __restrict__ out, int code) { out[0] = (float)code; }

extern "C" void kernel_launch(void* const* d_in, const int* in_sizes, int n_in,
                              void* d_out, int out_size, void* d_ws, size_t ws_size,
                              hipStream_t stream)
{
    const float* x    = (const float*)d_in[0];
    const float* prm  = (const float*)d_in[1];
    const float* W1   = (const float*)d_in[2];  const float* b1 = (const float*)d_in[3];
    const float* W2   = (const float*)d_in[4];  const float* b2 = (const float*)d_in[5];
    const float* W3   = (const float*)d_in[6];  const float* b3 = (const float*)d_in[7];
    const float* eW   = (const float*)d_in[8];  const float* eb = (const float*)d_in[9];
    const float* linW = (const float*)d_in[10]; const float* linB = (const float*)d_in[11];
    const float* log_dt = (const float*)d_in[12]; const float* logAre = (const float*)d_in[13];
    const float* Aim  = (const float*)d_in[14]; const float* Cre = (const float*)d_in[15];
    const float* Cim  = (const float*)d_in[16]; const float* Dskip = (const float*)d_in[17];
    const float* filmW= (const float*)d_in[18]; const float* filmB = (const float*)d_in[19];
    const float* resw = (const float*)d_in[20]; const float* cW = (const float*)d_in[21];
    const float* cb   = (const float*)d_in[22];

    double* sloc = (double*)d_ws;                                  // B*H*NC*16 = 2097152 d
    double* sini = sloc + (size_t)Bq*Hq*NCq*16;                    // 2097152 d
    double* pw   = sini + (size_t)Bq*Hq*NCq*16;                    // 2048 d
    double* pc2  = pw  + DEPq*Hq*Nq*2;                             // 2048 d
    double* pwL  = pc2 + DEPq*Hq*Nq*2;                             // 2048 d
    double* pwG  = pwL + DEPq*Hq*Nq*2;                             // 2048 d
    float* hbuf  = (float*)(pwG + DEPq*Hq*Nq*2);                   // B*L*H = 16777216 f
    float* ubuf  = hbuf + (size_t)Bq*Lq*Hq;                        // 16777216 f
    float* film  = ubuf + (size_t)Bq*Lq*Hq;                        // DEP*B*2H = 2048 f
    float* out   = (float*)d_out;
    size_t ws_needed = (char*)(film + DEPq*Bq*2*Hq) - (char*)d_ws;

    hipLaunchKernelGGL(k_cond_film, dim3(DEPq), dim3(512), 0, stream,
                       prm,W1,b1,W2,b2,W3,b3,filmW,filmB,film);
    hipLaunchKernelGGL(k_s4params, dim3(1), dim3(DEPq*Hq*Nq), 0, stream,
                       log_dt,logAre,Aim,Cre,Cim,pw,pc2,pwL,pwG);
    hipLaunchKernelGGL(k_expand, dim3(Bq*Lq/256), dim3(256), 0, stream, x,eW,eb,hbuf);
    for (int d=0; d<DEPq; d++){
        hipLaunchKernelGGL(k_mix,   dim3(Bq*Lq/256),      dim3(256), 0, stream,
                           hbuf, linW + d*Hq*Hq, linB + d*Hq, ubuf);
        hipLaunchKernelGGL(k_pass1, dim3(Bq*Hq*NCq/256),  dim3(256), 0, stream,
                           ubuf, pw + d*Hq*Nq*2, sloc);
        hipLaunchKernelGGL(k_pass2, dim3(Bq*Hq),          dim3(256), 0, stream,
                           sloc, pwL + d*Hq*Nq*2, pwG + d*Hq*Nq*2, sini);
        hipLaunchKernelGGL(k_pass3, dim3(Bq*Hq*NCq/256),  dim3(256), 0, stream,
                           ubuf, pw + d*Hq*Nq*2, pc2 + d*Hq*Nq*2, sini,
                           Dskip + d*Hq, film + d*Bq*2*Hq, resw + d*Hq, hbuf);
    }
    hipLaunchKernelGGL(k_contract, dim3(Bq*Lq/256), dim3(256), 0, stream, hbuf, x, cW, cb, out);

    static const int expected[23] = {
        Bq*Lq, Bq*2, 32, 16, 512, 32, 1024, 32, Hq, Hq,
        DEPq*Hq*Hq, DEPq*Hq, DEPq*Hq, DEPq*Hq*Nq, DEPq*Hq*Nq, DEPq*Hq*Nq, DEPq*Hq*Nq,
        DEPq*Hq, DEPq*2*Hq*32, DEPq*2*Hq, DEPq*Hq, Hq, 1
    };
    int code = 0;
    if (n_in != 23) code = 99;
    else { for (int i = 0; i < 23; i++) if (in_sizes[i] != expected[i]) { code = 100 + i; break; } }
    if (!code && ws_size < ws_needed) code = 200;
    if (code) hipLaunchKernelGGL(k_flag, dim3(1), dim3(1), 0, stream, out, code);
}

// Round 8
// 476.315 us; speedup vs baseline: 3.2432x; 1.2523x over previous
//
#include <hip/hip_runtime.h>
#include <math.h>

#define Bq 8
#define Lq 65536
#define Hq 32
#define Nq 8
#define DEPq 4
#define LCq 64
#define NCq (Lq/LCq)     // 1024 chunks per (b)
#define GRPq 32          // chunks per group in pass2
#define NGq  (NCq/GRPq)  // 32 groups
#define CPB  8           // chunks per block in scan kernels

// 32-wide dot from an LDS row (8 x ds_read_b128)
#define DOT32(res, W, tilerow) { \
  _Pragma("unroll") \
  for (int k_=0;k_<8;k_++){ float4 a_ = ((const float4*)(tilerow))[k_]; \
    res = fmaf(W[4*k_+0],a_.x,res); res = fmaf(W[4*k_+1],a_.y,res); \
    res = fmaf(W[4*k_+2],a_.z,res); res = fmaf(W[4*k_+3],a_.w,res);} }

// ---------------- conditioning MLP + FiLM ----------------
__global__ void k_cond_film(const float* __restrict__ prm,
                            const float* __restrict__ W1, const float* __restrict__ b1,
                            const float* __restrict__ W2, const float* __restrict__ b2,
                            const float* __restrict__ W3, const float* __restrict__ b3,
                            const float* __restrict__ filmW, const float* __restrict__ filmB,
                            float* __restrict__ film /* [DEP][B][2H] */)
{
    __shared__ float cond[Bq][32];
    int tid = threadIdx.x, d = blockIdx.x;
    if (tid < Bq) {
        float p0 = prm[tid*2+0], p1 = prm[tid*2+1];
        float c1[16];
        #pragma unroll
        for (int i=0;i<16;i++){ float v = W1[i*2+0]*p0 + W1[i*2+1]*p1 + b1[i]; c1[i]=v>0.f?v:0.f; }
        float c2[32];
        #pragma unroll
        for (int i=0;i<32;i++){ float a=b2[i];
            #pragma unroll
            for(int j=0;j<16;j++) a = fmaf(W2[i*16+j], c1[j], a);
            c2[i]=a>0.f?a:0.f; }
        #pragma unroll
        for (int i=0;i<32;i++){ float a=b3[i];
            #pragma unroll
            for(int j=0;j<32;j++) a = fmaf(W3[i*32+j], c2[j], a);
            cond[tid][i]=a>0.f?a:0.f; }
    }
    __syncthreads();
    int b = tid>>6, k = tid&63;
    float a = filmB[d*2*Hq + k];
    #pragma unroll
    for (int j=0;j<32;j++) a = fmaf(cond[b][j], filmW[(d*2*Hq + k)*32 + j], a);
    film[(d*Bq + b)*2*Hq + k] = a;
}

// ---------------- S4D derived params (f64 derivation, f32 tables) ----------------
__global__ void k_s4params(const float* __restrict__ log_dt, const float* __restrict__ logAre,
                           const float* __restrict__ Aim_, const float* __restrict__ Cre_,
                           const float* __restrict__ Cim_,
                           float* __restrict__ pw, float* __restrict__ pc2,
                           float* __restrict__ pwL, float* __restrict__ pwG)
{
    int idx = threadIdx.x; // DEP*H*N = 1024
    int d = idx/(Hq*Nq); int h = (idx/Nq)%Hq;
    double dt = exp((double)log_dt[d*Hq+h]);
    double Are = -exp((double)logAre[idx]);
    double Aim = (double)Aim_[idx];
    double dar = dt*Are, dai = dt*Aim;
    double er = exp(dar);
    double wr = er*cos(dai), wi = er*sin(dai);
    double em1r = wr - 1.0, em1i = wi;
    double den = Are*Are + Aim*Aim;
    double qr = (em1r*Are + em1i*Aim)/den;
    double qi = (em1i*Are - em1r*Aim)/den;
    double Cr = (double)Cre_[idx], Ci = (double)Cim_[idx];
    double eL = exp(dar*(double)LCq);
    double eG = exp(dar*(double)(LCq*GRPq));
    pw [idx*2+0]=(float)wr;  pw [idx*2+1]=(float)wi;
    pc2[idx*2+0]=(float)(2.0*(Cr*qr - Ci*qi)); pc2[idx*2+1]=(float)(2.0*(Cr*qi + Ci*qr));
    pwL[idx*2+0]=(float)(eL*cos(dai*(double)LCq));        pwL[idx*2+1]=(float)(eL*sin(dai*(double)LCq));
    pwG[idx*2+0]=(float)(eG*cos(dai*(double)(LCq*GRPq))); pwG[idx*2+1]=(float)(eG*sin(dai*(double)(LCq*GRPq)));
}

// ---------------- k_first: expand + mix_0 + chunk-local scan_0 -> sloc ----------------
__global__ __launch_bounds__(256) void k_first(
    const float* __restrict__ x, const float* __restrict__ eW, const float* __restrict__ eb,
    const float* __restrict__ linW, const float* __restrict__ linB,
    const float* __restrict__ pw, float* __restrict__ sloc)
{
    __shared__ float xt[CPB][LCq];
    __shared__ float tA[CPB][Hq];
    int tid = threadIdx.x;
    int h = tid & 31, g = tid >> 5;
    int cg = blockIdx.x*CPB + g;
    int b = cg >> 10, c = cg & (NCq-1);
    const float* xp = x + (size_t)b*Lq + (size_t)c*LCq;
    xt[g][h] = xp[h]; xt[g][32+h] = xp[32+h];
    float Wd[Hq];
    #pragma unroll
    for (int k=0;k<8;k++) ((float4*)Wd)[k] = ((const float4*)(linW + h*Hq))[k];
    float lb = linB[h], eWh = eW[h], ebh = eb[h];
    float wr[Nq],wi[Nq],sr[Nq],si[Nq];
    #pragma unroll
    for (int n=0;n<Nq;n++){ wr[n]=pw[(h*Nq+n)*2]; wi[n]=pw[(h*Nq+n)*2+1]; sr[n]=0.f; si[n]=0.f; }
    for (int j=0;j<LCq;j++){
        float h0 = fmaf(xt[g][j], eWh, ebh);
        tA[g][h] = h0;
        float u = lb;  DOT32(u, Wd, tA[g]);
        u = u>0.f?u:0.f;
        #pragma unroll
        for (int n=0;n<Nq;n++){
            float nr = fmaf(wr[n], sr[n], fmaf(-wi[n], si[n], u));
            float ni = fmaf(wr[n], si[n], wi[n]*sr[n]);
            sr[n]=nr; si[n]=ni;
        }
    }
    float* op = sloc + ((size_t)(b*Hq+h)*NCq + c)*16;
    #pragma unroll
    for (int n=0;n<Nq;n++){ op[n]=sr[n]; op[Nq+n]=si[n]; }
}

// ---------------- pass2: two-level prefix (f32), block per (b,h) ----------------
__global__ __launch_bounds__(256) void k_pass2(const float* __restrict__ sloc,
    const float* __restrict__ pwL, const float* __restrict__ pwG, float* __restrict__ sini)
{
    __shared__ float aux[NGq*Nq*2];
    int bid = blockIdx.x; int b = bid >> 5, h = bid & 31;
    const float* src = sloc + (size_t)(b*Hq+h)*NCq*16;
    float*       dst = sini + (size_t)(b*Hq+h)*NCq*16;
    int tid = threadIdx.x;
    int n = tid & 7, g2 = tid >> 3;   // g2 in [0,32)
    float wLr = pwL[(h*Nq+n)*2], wLi = pwL[(h*Nq+n)*2+1];
    float sr=0.f, si=0.f;
    for (int k=0;k<GRPq;k++){
        int c = g2*GRPq+k;
        float lr = src[c*16+n], li = src[c*16+8+n];
        float nr = fmaf(wLr,sr, fmaf(-wLi,si, lr));
        float ni = fmaf(wLr,si, fmaf( wLi,sr, li));
        sr=nr; si=ni;
    }
    aux[(g2*8+n)*2+0]=sr; aux[(g2*8+n)*2+1]=si;
    __syncthreads();
    if (tid < 8) {
        float wGr = pwG[(h*Nq+tid)*2], wGi = pwG[(h*Nq+tid)*2+1];
        float pr=0.f, pi=0.f;
        for (int g=0; g<NGq; g++){
            float er_ = aux[(g*8+tid)*2+0], ei_ = aux[(g*8+tid)*2+1];
            aux[(g*8+tid)*2+0]=pr; aux[(g*8+tid)*2+1]=pi;
            float nr = fmaf(wGr,pr, fmaf(-wGi,pi, er_));
            float ni = fmaf(wGr,pi, fmaf( wGi,pr, ei_));
            pr=nr; pi=ni;
        }
    }
    __syncthreads();
    sr = aux[(g2*8+n)*2+0]; si = aux[(g2*8+n)*2+1];
    for (int k=0;k<GRPq;k++){
        int c = g2*GRPq+k;
        float lr = src[c*16+n], li = src[c*16+8+n];
        dst[c*16+n] = sr; dst[c*16+8+n] = si;
        float nr = fmaf(wLr,sr, fmaf(-wLi,si, lr));
        float ni = fmaf(wLr,si, fmaf( wLi,sr, li));
        sr=nr; si=ni;
    }
}

// ---------------- k_main(d, d<3): seeded scan + film + relu + residual -> hbuf;
//                  plus mix_{d+1} + chunk-local scan_{d+1} -> sloc ----------------
__global__ __launch_bounds__(256) void k_main(
    const float* __restrict__ x, float* __restrict__ hbuf, int first,
    const float* __restrict__ eW, const float* __restrict__ eb,
    const float* __restrict__ linW_d, const float* __restrict__ linB_d,
    const float* __restrict__ linW_n, const float* __restrict__ linB_n,
    const float* __restrict__ pw_d, const float* __restrict__ pc2_d,
    const float* __restrict__ pw_n,
    const float* __restrict__ sini, float* __restrict__ sloc,
    const float* __restrict__ Dskip, const float* __restrict__ film,
    const float* __restrict__ resw)
{
    __shared__ float xt[CPB][LCq];
    __shared__ float tA[CPB][Hq];
    __shared__ float tB[CPB][Hq];
    int tid = threadIdx.x;
    int h = tid & 31, g = tid >> 5;
    int cg = blockIdx.x*CPB + g;
    int b = cg >> 10, c = cg & (NCq-1);
    size_t base = ((size_t)b*Lq + (size_t)c*LCq)*Hq + h;
    if (first) {
        const float* xp = x + (size_t)b*Lq + (size_t)c*LCq;
        xt[g][h] = xp[h]; xt[g][32+h] = xp[32+h];
    }
    float Wd[Hq], Wn[Hq];
    #pragma unroll
    for (int k=0;k<8;k++){
        ((float4*)Wd)[k] = ((const float4*)(linW_d + h*Hq))[k];
        ((float4*)Wn)[k] = ((const float4*)(linW_n + h*Hq))[k];
    }
    float lbd = linB_d[h], lbn = linB_n[h];
    float eWh = eW[h], ebh = eb[h];
    float wr[Nq],wi[Nq],cr[Nq],ci[Nq],sr[Nq],si[Nq],vr[Nq],vi[Nq],tr[Nq],ti[Nq];
    #pragma unroll
    for (int n=0;n<Nq;n++){
        wr[n]=pw_d[(h*Nq+n)*2]; wi[n]=pw_d[(h*Nq+n)*2+1];
        cr[n]=pc2_d[(h*Nq+n)*2]; ci[n]=pc2_d[(h*Nq+n)*2+1];
        vr[n]=pw_n[(h*Nq+n)*2]; vi[n]=pw_n[(h*Nq+n)*2+1];
        tr[n]=0.f; ti[n]=0.f;
    }
    const float* sp = sini + ((size_t)(b*Hq+h)*NCq + c)*16;
    #pragma unroll
    for (int n=0;n<Nq;n++){ sr[n]=sp[n]; si[n]=sp[Nq+n]; }
    float D = Dskip[h];
    float gf = film[b*2*Hq + h], bf = film[b*2*Hq + Hq + h];
    float rw = resw[h];
    for (int j=0;j<LCq;j++){
        float ho = first ? fmaf(xt[g][j], eWh, ebh) : hbuf[base + (size_t)j*Hq];
        tA[g][h] = ho;
        float u = lbd;  DOT32(u, Wd, tA[g]);
        u = u>0.f?u:0.f;
        float y = D*u;
        #pragma unroll
        for (int n=0;n<Nq;n++){
            float nr = fmaf(wr[n], sr[n], fmaf(-wi[n], si[n], u));
            float ni = fmaf(wr[n], si[n], wi[n]*sr[n]);
            sr[n]=nr; si[n]=ni;
            y = fmaf(cr[n], nr, y);
            y = fmaf(-ci[n], ni, y);
        }
        y = fmaf(y, gf, bf);
        y = y>0.f?y:0.f;
        float hn = fmaf(rw, ho, y);
        hbuf[base + (size_t)j*Hq] = hn;
        tB[g][h] = hn;
        float un = lbn;  DOT32(un, Wn, tB[g]);
        un = un>0.f?un:0.f;
        #pragma unroll
        for (int n=0;n<Nq;n++){
            float nr = fmaf(vr[n], tr[n], fmaf(-vi[n], ti[n], un));
            float ni = fmaf(vr[n], ti[n], vi[n]*tr[n]);
            tr[n]=nr; ti[n]=ni;
        }
    }
    float* op = sloc + ((size_t)(b*Hq+h)*NCq + c)*16;
    #pragma unroll
    for (int n=0;n<Nq;n++){ op[n]=tr[n]; op[Nq+n]=ti[n]; }
}

// ---------------- k_last (d=3): seeded scan + film + relu + residual + contract + tanh ----------------
__global__ __launch_bounds__(256) void k_last(
    const float* __restrict__ x, const float* __restrict__ hbuf,
    const float* __restrict__ linW_d, const float* __restrict__ linB_d,
    const float* __restrict__ pw_d, const float* __restrict__ pc2_d,
    const float* __restrict__ sini,
    const float* __restrict__ Dskip, const float* __restrict__ film,
    const float* __restrict__ resw, const float* __restrict__ cW,
    const float* __restrict__ cb, float* __restrict__ out)
{
    __shared__ float xt[CPB][LCq];
    __shared__ float tA[CPB][Hq];
    int tid = threadIdx.x;
    int h = tid & 31, g = tid >> 5;
    int cg = blockIdx.x*CPB + g;
    int b = cg >> 10, c = cg & (NCq-1);
    size_t base = ((size_t)b*Lq + (size_t)c*LCq)*Hq + h;
    const float* xp = x + (size_t)b*Lq + (size_t)c*LCq;
    xt[g][h] = xp[h]; xt[g][32+h] = xp[32+h];
    float Wd[Hq];
    #pragma unroll
    for (int k=0;k<8;k++) ((float4*)Wd)[k] = ((const float4*)(linW_d + h*Hq))[k];
    float lbd = linB_d[h];
    float wr[Nq],wi[Nq],cr[Nq],ci[Nq],sr[Nq],si[Nq];
    #pragma unroll
    for (int n=0;n<Nq;n++){
        wr[n]=pw_d[(h*Nq+n)*2]; wi[n]=pw_d[(h*Nq+n)*2+1];
        cr[n]=pc2_d[(h*Nq+n)*2]; ci[n]=pc2_d[(h*Nq+n)*2+1];
    }
    const float* sp = sini + ((size_t)(b*Hq+h)*NCq + c)*16;
    #pragma unroll
    for (int n=0;n<Nq;n++){ sr[n]=sp[n]; si[n]=sp[Nq+n]; }
    float D = Dskip[h];
    float gf = film[b*2*Hq + h], bf = film[b*2*Hq + Hq + h];
    float rw = resw[h];
    float cWh = cW[h], cb0 = cb[0];
    float* op = out + (size_t)b*Lq + (size_t)c*LCq;
    for (int j=0;j<LCq;j++){
        float ho = hbuf[base + (size_t)j*Hq];
        tA[g][h] = ho;
        float u = lbd;  DOT32(u, Wd, tA[g]);
        u = u>0.f?u:0.f;
        float y = D*u;
        #pragma unroll
        for (int n=0;n<Nq;n++){
            float nr = fmaf(wr[n], sr[n], fmaf(-wi[n], si[n], u));
            float ni = fmaf(wr[n], si[n], wi[n]*sr[n]);
            sr[n]=nr; si[n]=ni;
            y = fmaf(cr[n], nr, y);
            y = fmaf(-ci[n], ni, y);
        }
        y = fmaf(y, gf, bf);
        y = y>0.f?y:0.f;
        float hn = fmaf(rw, ho, y);
        float t = cWh*hn;
        #pragma unroll
        for (int m=16; m>=1; m>>=1) t += __shfl_xor(t, m, 64);
        if (h == 0) op[j] = xt[g][j]*tanhf(t + cb0);
    }
}

// ---------------- diagnostic flag ----------------
__global__ void k_flag(float* __restrict__ out, int code) { out[0] = (float)code; }

extern "C" void kernel_launch(void* const* d_in, const int* in_sizes, int n_in,
                              void* d_out, int out_size, void* d_ws, size_t ws_size,
                              hipStream_t stream)
{
    const float* x    = (const float*)d_in[0];
    const float* prm  = (const float*)d_in[1];
    const float* W1   = (const float*)d_in[2];  const float* b1 = (const float*)d_in[3];
    const float* W2   = (const float*)d_in[4];  const float* b2 = (const float*)d_in[5];
    const float* W3   = (const float*)d_in[6];  const float* b3 = (const float*)d_in[7];
    const float* eW   = (const float*)d_in[8];  const float* eb = (const float*)d_in[9];
    const float* linW = (const float*)d_in[10]; const float* linB = (const float*)d_in[11];
    const float* log_dt = (const float*)d_in[12]; const float* logAre = (const float*)d_in[13];
    const float* Aim  = (const float*)d_in[14]; const float* Cre = (const float*)d_in[15];
    const float* Cim  = (const float*)d_in[16]; const float* Dskip = (const float*)d_in[17];
    const float* filmW= (const float*)d_in[18]; const float* filmB = (const float*)d_in[19];
    const float* resw = (const float*)d_in[20]; const float* cW = (const float*)d_in[21];
    const float* cb   = (const float*)d_in[22];

    float* sloc = (float*)d_ws;                                    // B*H*NC*16 = 4194304 f
    float* sini = sloc + (size_t)Bq*Hq*NCq*16;                     // 4194304 f
    float* pw   = sini + (size_t)Bq*Hq*NCq*16;                     // 2048 f
    float* pc2  = pw  + DEPq*Hq*Nq*2;                              // 2048 f
    float* pwL  = pc2 + DEPq*Hq*Nq*2;                              // 2048 f
    float* pwG  = pwL + DEPq*Hq*Nq*2;                              // 2048 f
    float* film = pwG + DEPq*Hq*Nq*2;                              // DEP*B*2H = 2048 f
    float* hbuf = film + DEPq*Bq*2*Hq;                             // B*L*H = 16777216 f
    float* out  = (float*)d_out;
    size_t ws_needed = (char*)(hbuf + (size_t)Bq*Lq*Hq) - (char*)d_ws;

    const int scan_grid = Bq*NCq/CPB;   // 1024

    hipLaunchKernelGGL(k_cond_film, dim3(DEPq), dim3(512), 0, stream,
                       prm,W1,b1,W2,b2,W3,b3,filmW,filmB,film);
    hipLaunchKernelGGL(k_s4params, dim3(1), dim3(DEPq*Hq*Nq), 0, stream,
                       log_dt,logAre,Aim,Cre,Cim,pw,pc2,pwL,pwG);
    hipLaunchKernelGGL(k_first, dim3(scan_grid), dim3(256), 0, stream,
                       x, eW, eb, linW, linB, pw, sloc);
    for (int d=0; d<DEPq; d++){
        hipLaunchKernelGGL(k_pass2, dim3(Bq*Hq), dim3(256), 0, stream,
                           sloc, pwL + d*Hq*Nq*2, pwG + d*Hq*Nq*2, sini);
        if (d < DEPq-1) {
            hipLaunchKernelGGL(k_main, dim3(scan_grid), dim3(256), 0, stream,
                               x, hbuf, (d==0)?1:0, eW, eb,
                               linW + d*Hq*Hq, linB + d*Hq,
                               linW + (d+1)*Hq*Hq, linB + (d+1)*Hq,
                               pw + d*Hq*Nq*2, pc2 + d*Hq*Nq*2, pw + (d+1)*Hq*Nq*2,
                               sini, sloc,
                               Dskip + d*Hq, film + d*Bq*2*Hq, resw + d*Hq);
        } else {
            hipLaunchKernelGGL(k_last, dim3(scan_grid), dim3(256), 0, stream,
                               x, hbuf,
                               linW + d*Hq*Hq, linB + d*Hq,
                               pw + d*Hq*Nq*2, pc2 + d*Hq*Nq*2,
                               sini,
                               Dskip + d*Hq, film + d*Bq*2*Hq, resw + d*Hq,
                               cW, cb, out);
        }
    }

    static const int expected[23] = {
        Bq*Lq, Bq*2, 32, 16, 512, 32, 1024, 32, Hq, Hq,
        DEPq*Hq*Hq, DEPq*Hq, DEPq*Hq, DEPq*Hq*Nq, DEPq*Hq*Nq, DEPq*Hq*Nq, DEPq*Hq*Nq,
        DEPq*Hq, DEPq*2*Hq*32, DEPq*2*Hq, DEPq*Hq, Hq, 1
    };
    int code = 0;
    if (n_in != 23) code = 99;
    else { for (int i = 0; i < 23; i++) if (in_sizes[i] != expected[i]) { code = 100 + i; break; } }
    if (!code && ws_size < ws_needed) code = 200;
    if (code) hipLaunchKernelGGL(k_flag, dim3(1), dim3(1), 0, stream, out, code);
}